// Round 4
// baseline (828.654 us; speedup 1.0000x reference)
//
#include <hip/hip_runtime.h>
#include <math.h>

// Problem constants (validated against in_sizes at launch).
#define EPS 1e-5f

__device__ __forceinline__ float wave_sum64(float v) {
#pragma unroll
    for (int off = 32; off > 0; off >>= 1) v += __shfl_xor(v, off, 64);
    return v;
}

// ---------------------------------------------------------------------------
// K0: build CSR row pointer from a SORTED row array by boundary detection.
// ptr[i] = first edge index e with row[e] >= i  (ptr has n+1 entries).
// Each j in [0,n] is written exactly once -> race-free, deterministic.
// ---------------------------------------------------------------------------
__global__ __launch_bounds__(256) void build_rowptr(const int* __restrict__ row,
                                                    int* __restrict__ ptr,
                                                    int E, int n)
{
    int e = blockIdx.x * 256 + threadIdx.x;
    if (e >= E) return;
    int r = row[e];
    if (e == 0) {
        for (int j = 0; j <= r; ++j) ptr[j] = 0;
    }
    int rn = (e == E - 1) ? n : row[e + 1];
    for (int j = r + 1; j <= rn; ++j) ptr[j] = e + 1;
}

// ---------------------------------------------------------------------------
// K1: msg1 = x @ W1, msg2 = x @ W2   (x: [n,64], W: [64,64])
// Block 256 = 4 waves; each wave computes 4 nodes; W1/W2 staged in LDS.
// Lane j owns output feature j.
// ---------------------------------------------------------------------------
__global__ __launch_bounds__(256) void linear2(const float* __restrict__ x,
                                               const float* __restrict__ w1g,
                                               const float* __restrict__ w2g,
                                               float* __restrict__ m1,
                                               float* __restrict__ m2, int n)
{
    __shared__ float W1[4096];
    __shared__ float W2[4096];
    __shared__ float xb[4][4][64];
    const int tid = threadIdx.x;
    for (int idx = tid; idx < 4096; idx += 256) {
        W1[idx] = w1g[idx];
        W2[idx] = w2g[idx];
    }
    __syncthreads();
    const int wv = tid >> 6, lane = tid & 63;
    const int base = blockIdx.x * 16 + wv * 4;

#pragma unroll
    for (int nn = 0; nn < 4; ++nn) {
        int i = base + nn;
        xb[wv][nn][lane] = (i < n) ? x[(size_t)i * 64 + lane] : 0.f;
    }

    float a1[4] = {0.f, 0.f, 0.f, 0.f};
    float a2[4] = {0.f, 0.f, 0.f, 0.f};
#pragma unroll
    for (int kg = 0; kg < 16; ++kg) {
        float u1[4], u2[4];
#pragma unroll
        for (int t = 0; t < 4; ++t) {
            u1[t] = W1[(kg * 4 + t) * 64 + lane];
            u2[t] = W2[(kg * 4 + t) * 64 + lane];
        }
#pragma unroll
        for (int nn = 0; nn < 4; ++nn) {
            const float4 xv = *(const float4*)&xb[wv][nn][kg * 4];
            a1[nn] = fmaf(xv.x, u1[0], a1[nn]);
            a1[nn] = fmaf(xv.y, u1[1], a1[nn]);
            a1[nn] = fmaf(xv.z, u1[2], a1[nn]);
            a1[nn] = fmaf(xv.w, u1[3], a1[nn]);
            a2[nn] = fmaf(xv.x, u2[0], a2[nn]);
            a2[nn] = fmaf(xv.y, u2[1], a2[nn]);
            a2[nn] = fmaf(xv.z, u2[2], a2[nn]);
            a2[nn] = fmaf(xv.w, u2[3], a2[nn]);
        }
    }
#pragma unroll
    for (int nn = 0; nn < 4; ++nn) {
        int i = base + nn;
        if (i < n) {
            m1[(size_t)i * 64 + lane] = a1[nn];
            m2[(size_t)i * 64 + lane] = a2[nn];
        }
    }
}

// ---------------------------------------------------------------------------
// K2: PNA aggregation + combine. One wave handles 8 nodes.
//   per node: gather msg[col[e]] over its edge range, stats (sum/mean/max/std),
//   stats -> per-wave LDS transpose buffer, then feats[256] @ W[256x64] + b.
// FINAL pass additionally adds the partial (m1, staged in d_out), applies
// relu + LayerNorm (wave-wide shuffle reductions) and writes the final output.
// Dynamic LDS: 64 KB W + 64 KB stats (8 waves x 8 nodes x 256 f) = 128 KiB.
// ---------------------------------------------------------------------------
template <bool FINAL>
__global__ __launch_bounds__(512) void pna_agg(const float* __restrict__ msg,
                                               const int* __restrict__ rptr,
                                               const int* __restrict__ col,
                                               const float* __restrict__ Wg,
                                               const float* __restrict__ bias,
                                               const float* __restrict__ part,
                                               float* __restrict__ out,
                                               const float* __restrict__ gamma,
                                               const float* __restrict__ beta,
                                               int n)
{
    extern __shared__ float sm[];
    float* Wl = sm;            // 16384 floats = 64 KB
    float* st = sm + 16384;    // 8 waves * 8 nodes * 256 = 16384 floats

    const int tid = threadIdx.x;
    for (int idx = tid; idx < 16384; idx += 512) Wl[idx] = Wg[idx];
    __syncthreads();

    const int wv = tid >> 6, lane = tid & 63;
    float* stw = st + (size_t)wv * 8 * 256;
    const int base = blockIdx.x * 64 + wv * 8;

    // ---- gather + stats phase (per-wave private; no block barrier needed) ----
    for (int nn = 0; nn < 8; ++nn) {
        int i = base + nn;
        float s = 0.f, sq = 0.f, mx = -INFINITY;
        int cnt = 0;
        if (i < n) {
            int e0 = rptr[i], e1 = rptr[i + 1];
            cnt = e1 - e0;
            for (int e = e0; e < e1; e += 8) {
                int m = e1 - e;
                if (m > 8) m = 8;
                float g[8];
#pragma unroll
                for (int k = 0; k < 8; ++k)
                    if (k < m) g[k] = msg[(size_t)col[e + k] * 64 + lane];
#pragma unroll
                for (int k = 0; k < 8; ++k)
                    if (k < m) {
                        s += g[k];
                        sq = fmaf(g[k], g[k], sq);
                        mx = fmaxf(mx, g[k]);
                    }
            }
        }
        float cf = (cnt > 0) ? (float)cnt : 1.f;
        float mean = s / cf;
        float var = sq / cf - mean * mean;
        if (var < 0.f) var = 0.f;
        float sd = sqrtf(var + EPS);
        if (cnt == 0) mx = 0.f;
        stw[nn * 256 + lane]       = s;
        stw[nn * 256 + 64 + lane]  = mean;
        stw[nn * 256 + 128 + lane] = mx;
        stw[nn * 256 + 192 + lane] = sd;
    }

    // ---- combine phase: o[j=lane] = bias[j] + sum_f feats[f] * W[f][j] ----
    const float bj = bias[lane];
    float o[8];
#pragma unroll
    for (int nn = 0; nn < 8; ++nn) o[nn] = bj;

    for (int fg = 0; fg < 64; ++fg) {
        const float u0 = Wl[(fg * 4 + 0) * 64 + lane];
        const float u1 = Wl[(fg * 4 + 1) * 64 + lane];
        const float u2 = Wl[(fg * 4 + 2) * 64 + lane];
        const float u3 = Wl[(fg * 4 + 3) * 64 + lane];
#pragma unroll
        for (int nn = 0; nn < 8; ++nn) {
            const float4 f4 = *(const float4*)&stw[nn * 256 + fg * 4];
            o[nn] = fmaf(f4.x, u0, o[nn]);
            o[nn] = fmaf(f4.y, u1, o[nn]);
            o[nn] = fmaf(f4.z, u2, o[nn]);
            o[nn] = fmaf(f4.w, u3, o[nn]);
        }
    }

    // ---- epilogue ----
#pragma unroll
    for (int nn = 0; nn < 8; ++nn) {
        int i = base + nn;
        if (i >= n) continue;
        if (FINAL) {
            float r = o[nn] + part[(size_t)i * 64 + lane];  // m1 + m2
            r = fmaxf(r, 0.f);                               // relu
            float mu = wave_sum64(r) * (1.f / 64.f);
            float d = r - mu;
            float var = wave_sum64(d * d) * (1.f / 64.f);
            float rs = rsqrtf(var + EPS);
            out[(size_t)i * 64 + lane] = d * rs * gamma[lane] + beta[lane];
        } else {
            out[(size_t)i * 64 + lane] = o[nn];
        }
    }
}

// ---------------------------------------------------------------------------
extern "C" void kernel_launch(void* const* d_in, const int* in_sizes, int n_in,
                              void* d_out, int out_size, void* d_ws, size_t ws_size,
                              hipStream_t stream)
{
    const float* x     = (const float*)d_in[0];
    const float* w1    = (const float*)d_in[1];
    const float* w2    = (const float*)d_in[2];
    const float* pw1   = (const float*)d_in[3];
    const float* pb1   = (const float*)d_in[4];
    const float* pw2   = (const float*)d_in[5];
    const float* pb2   = (const float*)d_in[6];
    const float* gamma = (const float*)d_in[7];
    const float* beta  = (const float*)d_in[8];
    const int* nb_row  = (const int*)d_in[9];
    const int* nb_col  = (const int*)d_in[10];
    const int* cci_row = (const int*)d_in[11];
    const int* cci_col = (const int*)d_in[12];

    const int n  = in_sizes[0] / 64;   // 100000
    const int E1 = in_sizes[9];        // 1,000,000
    const int E2 = in_sizes[11];

    // workspace layout: msg1 [n*64 f32] | msg2 [n*64 f32] | ptr1 [n+1 i32] | ptr2 [n+1 i32]
    // total ~52 MB. d_out doubles as the m1 staging buffer.
    float* msg1 = (float*)d_ws;
    float* msg2 = msg1 + (size_t)n * 64;
    int*   ptr1 = (int*)(msg2 + (size_t)n * 64);
    int*   ptr2 = ptr1 + (n + 1);
    float* outf = (float*)d_out;

    // allow 128 KiB dynamic LDS (gfx950: 160 KiB/CU)
    (void)hipFuncSetAttribute((const void*)pna_agg<false>,
                              hipFuncAttributeMaxDynamicSharedMemorySize, 131072);
    (void)hipFuncSetAttribute((const void*)pna_agg<true>,
                              hipFuncAttributeMaxDynamicSharedMemorySize, 131072);

    build_rowptr<<<(E1 + 255) / 256, 256, 0, stream>>>(nb_row, ptr1, E1, n);
    build_rowptr<<<(E2 + 255) / 256, 256, 0, stream>>>(cci_row, ptr2, E2, n);
    linear2<<<(n + 15) / 16, 256, 0, stream>>>(x, w1, w2, msg1, msg2, n);

    pna_agg<false><<<(n + 63) / 64, 512, 131072, stream>>>(
        msg1, ptr1, nb_col, pw1, pb1, nullptr, outf, nullptr, nullptr, n);
    pna_agg<true><<<(n + 63) / 64, 512, 131072, stream>>>(
        msg2, ptr2, cci_col, pw2, pb2, outf, outf, gamma, beta, n);
}

// Round 5
// 570.676 us; speedup vs baseline: 1.4521x; 1.4521x over previous
//
#include <hip/hip_runtime.h>
#include <math.h>

#define EPS 1e-5f

typedef __attribute__((ext_vector_type(8))) short bf16x8;
typedef __attribute__((ext_vector_type(4))) float f32x4;

__device__ __forceinline__ ushort f2bf(float f) {
    union { float f; unsigned u; } v; v.f = f;
    unsigned u = v.u;
    return (ushort)((u + 0x7fffu + ((u >> 16) & 1u)) >> 16);  // RNE
}
__device__ __forceinline__ float bf2f(ushort h) {
    union { unsigned u; float f; } v; v.u = ((unsigned)h) << 16;
    return v.f;
}

// ---------------------------------------------------------------------------
// K0: CSR row pointer from SORTED row array (boundary detection).
// ---------------------------------------------------------------------------
__global__ __launch_bounds__(256) void build_rowptr(const int* __restrict__ row,
                                                    int* __restrict__ ptr,
                                                    int E, int n)
{
    int e = blockIdx.x * 256 + threadIdx.x;
    if (e >= E) return;
    int r = row[e];
    if (e == 0) {
        for (int j = 0; j <= r; ++j) ptr[j] = 0;
    }
    int rn = (e == E - 1) ? n : row[e + 1];
    for (int j = r + 1; j <= rn; ++j) ptr[j] = e + 1;
}

// ---------------------------------------------------------------------------
// K1: msg1 = bf16(x @ W1), msg2 = bf16(x @ W2)
// ---------------------------------------------------------------------------
__global__ __launch_bounds__(256) void linear2(const float* __restrict__ x,
                                               const float* __restrict__ w1g,
                                               const float* __restrict__ w2g,
                                               ushort* __restrict__ m1,
                                               ushort* __restrict__ m2, int n)
{
    __shared__ float W1[4096];
    __shared__ float W2[4096];
    __shared__ float xb[4][4][64];
    const int tid = threadIdx.x;
    for (int idx = tid; idx < 4096; idx += 256) {
        W1[idx] = w1g[idx];
        W2[idx] = w2g[idx];
    }
    __syncthreads();
    const int wv = tid >> 6, lane = tid & 63;
    const int base = blockIdx.x * 16 + wv * 4;

#pragma unroll
    for (int nn = 0; nn < 4; ++nn) {
        int i = base + nn;
        xb[wv][nn][lane] = (i < n) ? x[(size_t)i * 64 + lane] : 0.f;
    }

    float a1[4] = {0.f, 0.f, 0.f, 0.f};
    float a2[4] = {0.f, 0.f, 0.f, 0.f};
#pragma unroll
    for (int kg = 0; kg < 16; ++kg) {
        float u1[4], u2[4];
#pragma unroll
        for (int t = 0; t < 4; ++t) {
            u1[t] = W1[(kg * 4 + t) * 64 + lane];
            u2[t] = W2[(kg * 4 + t) * 64 + lane];
        }
#pragma unroll
        for (int nn = 0; nn < 4; ++nn) {
            const float4 xv = *(const float4*)&xb[wv][nn][kg * 4];
            a1[nn] = fmaf(xv.x, u1[0], a1[nn]);
            a1[nn] = fmaf(xv.y, u1[1], a1[nn]);
            a1[nn] = fmaf(xv.z, u1[2], a1[nn]);
            a1[nn] = fmaf(xv.w, u1[3], a1[nn]);
            a2[nn] = fmaf(xv.x, u2[0], a2[nn]);
            a2[nn] = fmaf(xv.y, u2[1], a2[nn]);
            a2[nn] = fmaf(xv.z, u2[2], a2[nn]);
            a2[nn] = fmaf(xv.w, u2[3], a2[nn]);
        }
    }
#pragma unroll
    for (int nn = 0; nn < 4; ++nn) {
        int i = base + nn;
        if (i < n) {
            m1[(size_t)i * 64 + lane] = f2bf(a1[nn]);
            m2[(size_t)i * 64 + lane] = f2bf(a2[nn]);
        }
    }
}

// ---------------------------------------------------------------------------
// K1b: W_T[n][k] = bf16(W[k][n]) for both PNA weights ([256,64] -> [64,256]).
// ---------------------------------------------------------------------------
__global__ __launch_bounds__(256) void prep_wt(const float* __restrict__ w1,
                                               const float* __restrict__ w2,
                                               ushort* __restrict__ wt1,
                                               ushort* __restrict__ wt2)
{
    int idx = blockIdx.x * 256 + threadIdx.x;
    if (idx < 64 * 256) {
        int k = idx >> 6, nn = idx & 63;
        wt1[nn * 256 + k] = f2bf(w1[idx]);
        wt2[nn * 256 + k] = f2bf(w2[idx]);
    }
}

// ---------------------------------------------------------------------------
// K2: PNA gather+stats (lane=feature) -> bf16 stats in swizzled LDS ->
//     MFMA combine (16 nodes/wave: M=16, K=256, N=64) -> epilogue.
// LDS: 8 waves x 16 nodes x 256 bf16 = 64 KB -> 2 blocks/CU, 16 waves/CU.
// Stats row layout: feature k at byte (2k) ^ ((node&7)<<4)  (bank-conflict-free
// for both the 64-lane b16 writes and the 16-row b128 A-frag reads).
// MFMA layout (gfx950 16x16x32): A[i][k]: i=lane&15, k=(lane>>4)*8+e;
// B[k][j]: j=lane&15, same k; D[r][c]: c=lane&15, r=(lane>>4)*4+reg (m89).
// ---------------------------------------------------------------------------
template <bool FINAL>
__global__ __launch_bounds__(512, 4) void pna_mfma(
    const ushort* __restrict__ msg,   // [n,64] bf16
    const int* __restrict__ rptr,
    const int* __restrict__ col,
    const ushort* __restrict__ wt,    // [64,256] bf16 (out-feature major)
    const float* __restrict__ bias,
    const float* __restrict__ part,   // FINAL: m1 partial (fp32), else unused
    float* __restrict__ out,
    const float* __restrict__ gamma,
    const float* __restrict__ beta,
    int n)
{
    __shared__ ushort st[8][16][256];  // 64 KB
    const int tid = threadIdx.x;
    const int wv = tid >> 6, lane = tid & 63;
    const int nodebase = blockIdx.x * 128 + wv * 16;

    // ---- phase 1: gather + stats (per-wave private; no block barrier) ----
    for (int nn = 0; nn < 16; ++nn) {
        int i = nodebase + nn;
        float s = 0.f, sq = 0.f, mx = -INFINITY;
        int cnt = 0;
        if (i < n) {
            int e0 = rptr[i], e1 = rptr[i + 1];
            cnt = e1 - e0;
            for (int e = e0; e < e1; e += 8) {
                int m = e1 - e;
                if (m > 8) m = 8;
                float g[8];
#pragma unroll
                for (int k = 0; k < 8; ++k)
                    if (k < m) g[k] = bf2f(msg[(size_t)col[e + k] * 64 + lane]);
#pragma unroll
                for (int k = 0; k < 8; ++k)
                    if (k < m) {
                        s += g[k];
                        sq = fmaf(g[k], g[k], sq);
                        mx = fmaxf(mx, g[k]);
                    }
            }
        }
        float cf = (cnt > 0) ? (float)cnt : 1.f;
        float mean = s / cf;
        float var = sq / cf - mean * mean;
        if (var < 0.f) var = 0.f;
        float sd = sqrtf(var + EPS);
        if (cnt == 0) mx = 0.f;

        char* rowp = (char*)&st[wv][nn][0];
        const int sw = (nn & 7) << 4;
        *(ushort*)(rowp + ((  0 + 2 * lane) ^ sw)) = f2bf(s);
        *(ushort*)(rowp + ((128 + 2 * lane) ^ sw)) = f2bf(mean);
        *(ushort*)(rowp + ((256 + 2 * lane) ^ sw)) = f2bf(mx);
        *(ushort*)(rowp + ((384 + 2 * lane) ^ sw)) = f2bf(sd);
    }

    // ---- phase 2: MFMA combine ----
    const int r = lane & 15, c = lane >> 4;
    f32x4 acc[4] = {{0.f,0.f,0.f,0.f},{0.f,0.f,0.f,0.f},
                    {0.f,0.f,0.f,0.f},{0.f,0.f,0.f,0.f}};
    const char* arow = (const char*)&st[wv][r][0];
    const int asw = (r & 7) << 4;
#pragma unroll
    for (int kt = 0; kt < 8; ++kt) {
        bf16x8 a = *(const bf16x8*)(arow + ((kt * 64 + c * 16) ^ asw));
#pragma unroll
        for (int nt = 0; nt < 4; ++nt) {
            bf16x8 b = *(const bf16x8*)&wt[(nt * 16 + r) * 256 + kt * 32 + c * 8];
            acc[nt] = __builtin_amdgcn_mfma_f32_16x16x32_bf16(a, b, acc[nt], 0, 0, 0);
        }
    }

    // ---- epilogue ----
    float biasv[4], gmv[4], btv[4];
#pragma unroll
    for (int nt = 0; nt < 4; ++nt) {
        biasv[nt] = bias[nt * 16 + r];
        if (FINAL) {
            gmv[nt] = gamma[nt * 16 + r];
            btv[nt] = beta[nt * 16 + r];
        }
    }
#pragma unroll
    for (int e = 0; e < 4; ++e) {
        const int i = nodebase + c * 4 + e;
        if (!FINAL) {
            if (i < n) {
#pragma unroll
                for (int nt = 0; nt < 4; ++nt)
                    out[(size_t)i * 64 + nt * 16 + r] = acc[nt][e] + biasv[nt];
            }
        } else {
            float v[4];
            float sum = 0.f;
#pragma unroll
            for (int nt = 0; nt < 4; ++nt) {
                float t = 0.f;
                if (i < n)
                    t = fmaxf(acc[nt][e] + biasv[nt] +
                              part[(size_t)i * 64 + nt * 16 + r], 0.f);
                v[nt] = t;
                sum += t;
            }
            sum += __shfl_xor(sum, 1);
            sum += __shfl_xor(sum, 2);
            sum += __shfl_xor(sum, 4);
            sum += __shfl_xor(sum, 8);
            const float mu = sum * (1.f / 64.f);
            float sqs = 0.f;
#pragma unroll
            for (int nt = 0; nt < 4; ++nt) {
                float d = v[nt] - mu;
                sqs += d * d;
            }
            sqs += __shfl_xor(sqs, 1);
            sqs += __shfl_xor(sqs, 2);
            sqs += __shfl_xor(sqs, 4);
            sqs += __shfl_xor(sqs, 8);
            const float rs = rsqrtf(sqs * (1.f / 64.f) + EPS);
            if (i < n) {
#pragma unroll
                for (int nt = 0; nt < 4; ++nt)
                    out[(size_t)i * 64 + nt * 16 + r] =
                        (v[nt] - mu) * rs * gmv[nt] + btv[nt];
            }
        }
    }
}

// ---------------------------------------------------------------------------
extern "C" void kernel_launch(void* const* d_in, const int* in_sizes, int n_in,
                              void* d_out, int out_size, void* d_ws, size_t ws_size,
                              hipStream_t stream)
{
    const float* x     = (const float*)d_in[0];
    const float* w1    = (const float*)d_in[1];
    const float* w2    = (const float*)d_in[2];
    const float* pw1   = (const float*)d_in[3];
    const float* pb1   = (const float*)d_in[4];
    const float* pw2   = (const float*)d_in[5];
    const float* pb2   = (const float*)d_in[6];
    const float* gamma = (const float*)d_in[7];
    const float* beta  = (const float*)d_in[8];
    const int* nb_row  = (const int*)d_in[9];
    const int* nb_col  = (const int*)d_in[10];
    const int* cci_row = (const int*)d_in[11];
    const int* cci_col = (const int*)d_in[12];

    const int n  = in_sizes[0] / 64;   // 100000
    const int E1 = in_sizes[9];        // 1,000,000
    const int E2 = in_sizes[11];

    // workspace: msg1/msg2 bf16 [n*64] | ptr1/ptr2 [n+1] | wt1/wt2 bf16 [16384]
    char* p = (char*)d_ws;
    ushort* msg1 = (ushort*)p;  p += (size_t)n * 64 * sizeof(ushort);
    ushort* msg2 = (ushort*)p;  p += (size_t)n * 64 * sizeof(ushort);
    int* ptr1 = (int*)p;        p += (size_t)(n + 1) * sizeof(int);
    int* ptr2 = (int*)p;        p += (size_t)(n + 1) * sizeof(int);
    p = (char*)(((uintptr_t)p + 63) & ~(uintptr_t)63);
    ushort* wt1 = (ushort*)p;   p += 64 * 256 * sizeof(ushort);
    ushort* wt2 = (ushort*)p;
    float* outf = (float*)d_out;

    build_rowptr<<<(E1 + 255) / 256, 256, 0, stream>>>(nb_row, ptr1, E1, n);
    build_rowptr<<<(E2 + 255) / 256, 256, 0, stream>>>(cci_row, ptr2, E2, n);
    prep_wt<<<64, 256, 0, stream>>>(pw1, pw2, wt1, wt2);
    linear2<<<(n + 15) / 16, 256, 0, stream>>>(x, w1, w2, msg1, msg2, n);

    const int grid = (n + 127) / 128;
    pna_mfma<false><<<grid, 512, 0, stream>>>(
        msg1, ptr1, nb_col, wt1, pb1, nullptr, outf, nullptr, nullptr, n);
    pna_mfma<true><<<grid, 512, 0, stream>>>(
        msg2, ptr2, cci_col, wt2, pb2, outf, outf, gamma, beta, n);
}

// Round 6
// 276.745 us; speedup vs baseline: 2.9943x; 2.0621x over previous
//
#include <hip/hip_runtime.h>
#include <math.h>

#define EPS 1e-5f

typedef __attribute__((ext_vector_type(8))) short bf16x8;
typedef __attribute__((ext_vector_type(4))) float f32x4;

__device__ __forceinline__ ushort f2bf(float f) {
    union { float f; unsigned u; } v; v.f = f;
    unsigned u = v.u;
    return (ushort)((u + 0x7fffu + ((u >> 16) & 1u)) >> 16);  // RNE
}
__device__ __forceinline__ float bf2f(ushort h) {
    union { unsigned u; float f; } v; v.u = ((unsigned)h) << 16;
    return v.f;
}
__device__ __forceinline__ uint packbf(float a, float b) {
    return (uint)f2bf(a) | ((uint)f2bf(b) << 16);
}

// ---------------------------------------------------------------------------
// K0: CSR row pointer from SORTED row array (boundary detection).
// ---------------------------------------------------------------------------
__global__ __launch_bounds__(256) void build_rowptr(const int* __restrict__ row,
                                                    int* __restrict__ ptr,
                                                    int E, int n)
{
    int e = blockIdx.x * 256 + threadIdx.x;
    if (e >= E) return;
    int r = row[e];
    if (e == 0) {
        for (int j = 0; j <= r; ++j) ptr[j] = 0;
    }
    int rn = (e == E - 1) ? n : row[e + 1];
    for (int j = r + 1; j <= rn; ++j) ptr[j] = e + 1;
}

// ---------------------------------------------------------------------------
// K1: msg1 = bf16(x @ W1), msg2 = bf16(x @ W2)
// ---------------------------------------------------------------------------
__global__ __launch_bounds__(256) void linear2(const float* __restrict__ x,
                                               const float* __restrict__ w1g,
                                               const float* __restrict__ w2g,
                                               ushort* __restrict__ m1,
                                               ushort* __restrict__ m2, int n)
{
    __shared__ float W1[4096];
    __shared__ float W2[4096];
    __shared__ float xb[4][4][64];
    const int tid = threadIdx.x;
    for (int idx = tid; idx < 4096; idx += 256) {
        W1[idx] = w1g[idx];
        W2[idx] = w2g[idx];
    }
    __syncthreads();
    const int wv = tid >> 6, lane = tid & 63;
    const int base = blockIdx.x * 16 + wv * 4;

#pragma unroll
    for (int nn = 0; nn < 4; ++nn) {
        int i = base + nn;
        xb[wv][nn][lane] = (i < n) ? x[(size_t)i * 64 + lane] : 0.f;
    }

    float a1[4] = {0.f, 0.f, 0.f, 0.f};
    float a2[4] = {0.f, 0.f, 0.f, 0.f};
#pragma unroll
    for (int kg = 0; kg < 16; ++kg) {
        float u1[4], u2[4];
#pragma unroll
        for (int t = 0; t < 4; ++t) {
            u1[t] = W1[(kg * 4 + t) * 64 + lane];
            u2[t] = W2[(kg * 4 + t) * 64 + lane];
        }
#pragma unroll
        for (int nn = 0; nn < 4; ++nn) {
            const float4 xv = *(const float4*)&xb[wv][nn][kg * 4];
            a1[nn] = fmaf(xv.x, u1[0], a1[nn]);
            a1[nn] = fmaf(xv.y, u1[1], a1[nn]);
            a1[nn] = fmaf(xv.z, u1[2], a1[nn]);
            a1[nn] = fmaf(xv.w, u1[3], a1[nn]);
            a2[nn] = fmaf(xv.x, u2[0], a2[nn]);
            a2[nn] = fmaf(xv.y, u2[1], a2[nn]);
            a2[nn] = fmaf(xv.z, u2[2], a2[nn]);
            a2[nn] = fmaf(xv.w, u2[3], a2[nn]);
        }
    }
#pragma unroll
    for (int nn = 0; nn < 4; ++nn) {
        int i = base + nn;
        if (i < n) {
            m1[(size_t)i * 64 + lane] = f2bf(a1[nn]);
            m2[(size_t)i * 64 + lane] = f2bf(a2[nn]);
        }
    }
}

// ---------------------------------------------------------------------------
// K1b: W_T[n][k] = bf16(W[k][n]) for both PNA weights ([256,64] -> [64,256]).
// ---------------------------------------------------------------------------
__global__ __launch_bounds__(256) void prep_wt(const float* __restrict__ w1,
                                               const float* __restrict__ w2,
                                               ushort* __restrict__ wt1,
                                               ushort* __restrict__ wt2)
{
    int idx = blockIdx.x * 256 + threadIdx.x;
    if (idx < 64 * 256) {
        int k = idx >> 6, nn = idx & 63;
        wt1[nn * 256 + k] = f2bf(w1[idx]);
        wt2[nn * 256 + k] = f2bf(w2[idx]);
    }
}

// ---------------------------------------------------------------------------
// K2: PNA gather+stats -> bf16 stats in swizzled LDS -> MFMA combine -> epi.
// Gather: lane pairs. Lanes 0-31 process even edges, 32-63 odd edges; each
// lane loads 2 features (uint). 8 unconditional loads = 16 edges in flight.
// Invalid slots redirected to row 0 (L1-hot). Halves combined via shfl_xor 32.
// LDS: 8 waves x 16 nodes x 256 bf16 = 64 KB -> 2 blocks/CU.
// MFMA layout (gfx950 16x16x32, m89): A i=lane&15, k=(lane>>4)*8+e;
// B j=lane&15; D c=lane&15, r=(lane>>4)*4+reg.
// ---------------------------------------------------------------------------
template <bool FINAL>
__global__ __launch_bounds__(512, 4) void pna_mfma(
    const ushort* __restrict__ msg,   // [n,64] bf16
    const int* __restrict__ rptr,
    const int* __restrict__ col,
    const ushort* __restrict__ wt,    // [64,256] bf16 (out-feature major)
    const float* __restrict__ bias,
    const float* __restrict__ part,   // FINAL: m1 partial (fp32), else unused
    float* __restrict__ out,
    const float* __restrict__ gamma,
    const float* __restrict__ beta,
    int n, int E)
{
    __shared__ ushort st[8][16][256];  // 64 KB
    const int tid = threadIdx.x;
    const int wv = tid >> 6, lane = tid & 63;
    const int half = lane >> 5;       // 0: even edges, 1: odd edges
    const int l32 = lane & 31;        // feature-pair index (features 2*l32, 2*l32+1)
    const uint lanoff = (uint)l32 << 2;
    const int nodebase = blockIdx.x * 128 + wv * 16;
    const char* msgc = (const char*)msg;

    // prefetch 17 row pointers for this wave's nodes
    int rpidx = nodebase + (lane & 31);
    if (rpidx > n) rpidx = n;
    const int rpv = rptr[rpidx];

    // ---- phase 1: gather + stats ----
    for (int nn = 0; nn < 16; ++nn) {
        const int i = nodebase + nn;
        float s0 = 0.f, s1 = 0.f, q0 = 0.f, q1 = 0.f;
        float m0 = -INFINITY, m1v = -INFINITY;
        int cnt = 0;
        if (i < n) {
            const int e0 = __shfl(rpv, nn, 64);
            const int e1 = __shfl(rpv, nn + 1, 64);
            cnt = e1 - e0;
            for (int eb = e0; eb < e1; eb += 16) {
                const int rem = e1 - eb;
                // batch col prefetch: lane j (j = lane&15) loads col[eb+j]
                int cidx = eb + (lane & 15);
                if (cidx > E - 1) cidx = E - 1;
                const int colv = col[cidx];
                uint g[8];
#pragma unroll
                for (int t = 0; t < 8; ++t) {
                    const int j = 2 * t + half;
                    const int c = __shfl(colv, j, 64);
                    const uint off = (j < rem) ? (((uint)c << 7) + lanoff) : lanoff;
                    g[t] = *(const uint*)(msgc + off);
                }
#pragma unroll
                for (int t = 0; t < 8; ++t) {
                    const int j = 2 * t + half;
                    const bool valid = j < rem;
                    float a = bf2f((ushort)(g[t] & 0xffffu));
                    float b = bf2f((ushort)(g[t] >> 16));
                    const float am = valid ? a : 0.f;
                    const float bm = valid ? b : 0.f;
                    s0 += am; q0 = fmaf(am, am, q0);
                    s1 += bm; q1 = fmaf(bm, bm, q1);
                    m0 = fmaxf(m0, valid ? a : -INFINITY);
                    m1v = fmaxf(m1v, valid ? b : -INFINITY);
                }
            }
        }
        // combine even/odd halves
        s0 += __shfl_xor(s0, 32, 64);  s1 += __shfl_xor(s1, 32, 64);
        q0 += __shfl_xor(q0, 32, 64);  q1 += __shfl_xor(q1, 32, 64);
        m0  = fmaxf(m0,  __shfl_xor(m0, 32, 64));
        m1v = fmaxf(m1v, __shfl_xor(m1v, 32, 64));

        const float cf = (cnt > 0) ? (float)cnt : 1.f;
        const float inv = 1.f / cf;
        const float mean0 = s0 * inv, mean1 = s1 * inv;
        float v0 = q0 * inv - mean0 * mean0; if (v0 < 0.f) v0 = 0.f;
        float v1 = q1 * inv - mean1 * mean1; if (v1 < 0.f) v1 = 0.f;
        const float sd0 = sqrtf(v0 + EPS), sd1 = sqrtf(v1 + EPS);
        if (cnt == 0) { m0 = 0.f; m1v = 0.f; }

        char* rowp = (char*)&st[wv][nn][0];
        const int sw = (nn & 7) << 4;
        if (half == 0) {
            *(uint*)(rowp + ((0 + (int)lanoff) ^ sw))   = packbf(s0, s1);
            *(uint*)(rowp + ((256 + (int)lanoff) ^ sw)) = packbf(m0, m1v);
        } else {
            *(uint*)(rowp + ((128 + (int)lanoff) ^ sw)) = packbf(mean0, mean1);
            *(uint*)(rowp + ((384 + (int)lanoff) ^ sw)) = packbf(sd0, sd1);
        }
    }

    // ---- phase 2: MFMA combine ----
    const int r = lane & 15, c = lane >> 4;
    f32x4 acc[4] = {{0.f,0.f,0.f,0.f},{0.f,0.f,0.f,0.f},
                    {0.f,0.f,0.f,0.f},{0.f,0.f,0.f,0.f}};
    const char* arow = (const char*)&st[wv][r][0];
    const int asw = (r & 7) << 4;
#pragma unroll
    for (int kt = 0; kt < 8; ++kt) {
        bf16x8 a = *(const bf16x8*)(arow + ((kt * 64 + c * 16) ^ asw));
#pragma unroll
        for (int nt = 0; nt < 4; ++nt) {
            bf16x8 b = *(const bf16x8*)&wt[(nt * 16 + r) * 256 + kt * 32 + c * 8];
            acc[nt] = __builtin_amdgcn_mfma_f32_16x16x32_bf16(a, b, acc[nt], 0, 0, 0);
        }
    }

    // ---- epilogue ----
    float biasv[4], gmv[4], btv[4];
#pragma unroll
    for (int nt = 0; nt < 4; ++nt) {
        biasv[nt] = bias[nt * 16 + r];
        if (FINAL) {
            gmv[nt] = gamma[nt * 16 + r];
            btv[nt] = beta[nt * 16 + r];
        }
    }
#pragma unroll
    for (int e = 0; e < 4; ++e) {
        const int i = nodebase + c * 4 + e;
        if (!FINAL) {
            if (i < n) {
#pragma unroll
                for (int nt = 0; nt < 4; ++nt)
                    out[(size_t)i * 64 + nt * 16 + r] = acc[nt][e] + biasv[nt];
            }
        } else {
            float v[4];
            float sum = 0.f;
#pragma unroll
            for (int nt = 0; nt < 4; ++nt) {
                float t = 0.f;
                if (i < n)
                    t = fmaxf(acc[nt][e] + biasv[nt] +
                              part[(size_t)i * 64 + nt * 16 + r], 0.f);
                v[nt] = t;
                sum += t;
            }
            sum += __shfl_xor(sum, 1);
            sum += __shfl_xor(sum, 2);
            sum += __shfl_xor(sum, 4);
            sum += __shfl_xor(sum, 8);
            const float mu = sum * (1.f / 64.f);
            float sqs = 0.f;
#pragma unroll
            for (int nt = 0; nt < 4; ++nt) {
                float d = v[nt] - mu;
                sqs += d * d;
            }
            sqs += __shfl_xor(sqs, 1);
            sqs += __shfl_xor(sqs, 2);
            sqs += __shfl_xor(sqs, 4);
            sqs += __shfl_xor(sqs, 8);
            const float rs = rsqrtf(sqs * (1.f / 64.f) + EPS);
            if (i < n) {
#pragma unroll
                for (int nt = 0; nt < 4; ++nt)
                    out[(size_t)i * 64 + nt * 16 + r] =
                        (v[nt] - mu) * rs * gmv[nt] + btv[nt];
            }
        }
    }
}

// ---------------------------------------------------------------------------
extern "C" void kernel_launch(void* const* d_in, const int* in_sizes, int n_in,
                              void* d_out, int out_size, void* d_ws, size_t ws_size,
                              hipStream_t stream)
{
    const float* x     = (const float*)d_in[0];
    const float* w1    = (const float*)d_in[1];
    const float* w2    = (const float*)d_in[2];
    const float* pw1   = (const float*)d_in[3];
    const float* pb1   = (const float*)d_in[4];
    const float* pw2   = (const float*)d_in[5];
    const float* pb2   = (const float*)d_in[6];
    const float* gamma = (const float*)d_in[7];
    const float* beta  = (const float*)d_in[8];
    const int* nb_row  = (const int*)d_in[9];
    const int* nb_col  = (const int*)d_in[10];
    const int* cci_row = (const int*)d_in[11];
    const int* cci_col = (const int*)d_in[12];

    const int n  = in_sizes[0] / 64;   // 100000
    const int E1 = in_sizes[9];        // 1,000,000
    const int E2 = in_sizes[11];

    // workspace: msg1/msg2 bf16 [n*64] | ptr1/ptr2 [n+1] | wt1/wt2 bf16 [16384]
    char* p = (char*)d_ws;
    ushort* msg1 = (ushort*)p;  p += (size_t)n * 64 * sizeof(ushort);
    ushort* msg2 = (ushort*)p;  p += (size_t)n * 64 * sizeof(ushort);
    int* ptr1 = (int*)p;        p += (size_t)(n + 1) * sizeof(int);
    int* ptr2 = (int*)p;        p += (size_t)(n + 1) * sizeof(int);
    p = (char*)(((uintptr_t)p + 63) & ~(uintptr_t)63);
    ushort* wt1 = (ushort*)p;   p += 64 * 256 * sizeof(ushort);
    ushort* wt2 = (ushort*)p;
    float* outf = (float*)d_out;

    build_rowptr<<<(E1 + 255) / 256, 256, 0, stream>>>(nb_row, ptr1, E1, n);
    build_rowptr<<<(E2 + 255) / 256, 256, 0, stream>>>(cci_row, ptr2, E2, n);
    prep_wt<<<64, 256, 0, stream>>>(pw1, pw2, wt1, wt2);
    linear2<<<(n + 15) / 16, 256, 0, stream>>>(x, w1, w2, msg1, msg2, n);

    const int grid = (n + 127) / 128;
    pna_mfma<false><<<grid, 512, 0, stream>>>(
        msg1, ptr1, nb_col, wt1, pb1, nullptr, outf, nullptr, nullptr, n, E1);
    pna_mfma<true><<<grid, 512, 0, stream>>>(
        msg2, ptr2, cci_col, wt2, pb2, outf, outf, gamma, beta, n, E2);
}

// Round 7
// 199.547 us; speedup vs baseline: 4.1527x; 1.3869x over previous
//
#include <hip/hip_runtime.h>
#include <math.h>

#define EPS 1e-5f

typedef __attribute__((ext_vector_type(8))) short bf16x8;
typedef __attribute__((ext_vector_type(4))) float f32x4;

__device__ __forceinline__ ushort f2bf(float f) {
    union { float f; unsigned u; } v; v.f = f;
    unsigned u = v.u;
    return (ushort)((u + 0x7fffu + ((u >> 16) & 1u)) >> 16);  // RNE
}
__device__ __forceinline__ float bf2f(ushort h) {
    union { unsigned u; float f; } v; v.u = ((unsigned)h) << 16;
    return v.f;
}
__device__ __forceinline__ uint packbf(float a, float b) {
    return (uint)f2bf(a) | ((uint)f2bf(b) << 16);
}

// ---------------------------------------------------------------------------
// K0: CSR row pointer from SORTED row array (boundary detection).
// ---------------------------------------------------------------------------
__global__ __launch_bounds__(256) void build_rowptr(const int* __restrict__ row,
                                                    int* __restrict__ ptr,
                                                    int E, int n)
{
    int e = blockIdx.x * 256 + threadIdx.x;
    if (e >= E) return;
    int r = row[e];
    if (e == 0) {
        for (int j = 0; j <= r; ++j) ptr[j] = 0;
    }
    int rn = (e == E - 1) ? n : row[e + 1];
    for (int j = r + 1; j <= rn; ++j) ptr[j] = e + 1;
}

// ---------------------------------------------------------------------------
// K1: transpose + bf16-cast all weights.
//  pna:  wt[j][k]  = W[k][j]   ([256,64] -> [64,256])
//  lin:  wtl[j][k] = W[k][j]   ([64,64]  -> [64,64])
// ---------------------------------------------------------------------------
__global__ __launch_bounds__(256) void prep_w(const float* __restrict__ pw1,
                                              const float* __restrict__ pw2,
                                              const float* __restrict__ w1,
                                              const float* __restrict__ w2,
                                              ushort* __restrict__ wt1,
                                              ushort* __restrict__ wt2,
                                              ushort* __restrict__ wtl1,
                                              ushort* __restrict__ wtl2)
{
    int idx = blockIdx.x * 256 + threadIdx.x;
    if (idx < 16384) {
        int k = idx >> 6, j = idx & 63;
        wt1[j * 256 + k] = f2bf(pw1[idx]);
        wt2[j * 256 + k] = f2bf(pw2[idx]);
    }
    if (idx < 4096) {
        int k = idx >> 6, j = idx & 63;
        wtl1[j * 64 + k] = f2bf(w1[idx]);
        wtl2[j * 64 + k] = f2bf(w2[idx]);
    }
}

// ---------------------------------------------------------------------------
// K2: msg1/msg2 = bf16(x @ W1/W2) via MFMA. One wave = 16 nodes (M=16,K=64,
// N=64). A from global fp32 x (cast), B from transposed bf16 weights.
// MFMA 16x16x32 layout (m89): A i=lane&15, k=(lane>>4)*8+e; B j=lane&15;
// D col=lane&15, row=(lane>>4)*4+reg. No LDS, no barriers.
// ---------------------------------------------------------------------------
__global__ __launch_bounds__(512) void linear_mfma(const float* __restrict__ x,
                                                   const ushort* __restrict__ wtl1,
                                                   const ushort* __restrict__ wtl2,
                                                   ushort* __restrict__ m1,
                                                   ushort* __restrict__ m2, int n)
{
    const int tid = threadIdx.x, wv = tid >> 6, lane = tid & 63;
    const int r = lane & 15, c = lane >> 4;
    const int nodebase = blockIdx.x * 128 + wv * 16;
    const int anode = nodebase + r;

    bf16x8 a[2];
#pragma unroll
    for (int kt = 0; kt < 2; ++kt) {
        float4 lo = {0.f, 0.f, 0.f, 0.f}, hi = {0.f, 0.f, 0.f, 0.f};
        if (anode < n) {
            lo = *(const float4*)&x[(size_t)anode * 64 + kt * 32 + c * 8];
            hi = *(const float4*)&x[(size_t)anode * 64 + kt * 32 + c * 8 + 4];
        }
        ushort t[8] = {f2bf(lo.x), f2bf(lo.y), f2bf(lo.z), f2bf(lo.w),
                       f2bf(hi.x), f2bf(hi.y), f2bf(hi.z), f2bf(hi.w)};
        a[kt] = *(const bf16x8*)t;
    }

    f32x4 acc1[4] = {{0.f,0.f,0.f,0.f},{0.f,0.f,0.f,0.f},
                     {0.f,0.f,0.f,0.f},{0.f,0.f,0.f,0.f}};
    f32x4 acc2[4] = {{0.f,0.f,0.f,0.f},{0.f,0.f,0.f,0.f},
                     {0.f,0.f,0.f,0.f},{0.f,0.f,0.f,0.f}};
#pragma unroll
    for (int kt = 0; kt < 2; ++kt) {
#pragma unroll
        for (int nt = 0; nt < 4; ++nt) {
            bf16x8 b1 = *(const bf16x8*)&wtl1[(nt * 16 + r) * 64 + kt * 32 + c * 8];
            bf16x8 b2 = *(const bf16x8*)&wtl2[(nt * 16 + r) * 64 + kt * 32 + c * 8];
            acc1[nt] = __builtin_amdgcn_mfma_f32_16x16x32_bf16(a[kt], b1, acc1[nt], 0, 0, 0);
            acc2[nt] = __builtin_amdgcn_mfma_f32_16x16x32_bf16(a[kt], b2, acc2[nt], 0, 0, 0);
        }
    }

#pragma unroll
    for (int e = 0; e < 4; ++e) {
        const int i = nodebase + c * 4 + e;
        if (i < n) {
#pragma unroll
            for (int nt = 0; nt < 4; ++nt) {
                m1[(size_t)i * 64 + nt * 16 + r] = f2bf(acc1[nt][e]);
                m2[(size_t)i * 64 + nt * 16 + r] = f2bf(acc2[nt][e]);
            }
        }
    }
}

// ---------------------------------------------------------------------------
// One PNA aggregation pass: gather+stats into per-wave LDS, then MFMA into acc.
// Per-wave private -> no block barriers (same-wave DS ordering is in-order).
// ---------------------------------------------------------------------------
__device__ __forceinline__ void agg_pass(const ushort* __restrict__ msg,
                                         const int* __restrict__ col,
                                         const ushort* __restrict__ wt,
                                         int rpv, ushort (*stw)[256],
                                         f32x4 acc[4],
                                         int nodebase, int lane, int n, int E)
{
    const int half = lane >> 5;
    const int l32 = lane & 31;
    const uint lanoff = (uint)l32 << 2;
    const char* msgc = (const char*)msg;

    for (int nn = 0; nn < 16; ++nn) {
        const int i = nodebase + nn;
        float s0 = 0.f, s1 = 0.f, q0 = 0.f, q1 = 0.f;
        float m0 = -INFINITY, m1v = -INFINITY;
        int cnt = 0;
        if (i < n) {
            const int e0 = __shfl(rpv, nn, 64);
            const int e1 = __shfl(rpv, nn + 1, 64);
            cnt = e1 - e0;
            for (int eb = e0; eb < e1; eb += 16) {
                const int rem = e1 - eb;
                int cidx = eb + (lane & 15);
                if (cidx > E - 1) cidx = E - 1;
                const int colv = col[cidx];
                uint g[8];
#pragma unroll
                for (int t = 0; t < 8; ++t) {
                    const int j = 2 * t + half;
                    const int cc = __shfl(colv, j, 64);
                    const uint off = (j < rem) ? (((uint)cc << 7) + lanoff) : lanoff;
                    g[t] = *(const uint*)(msgc + off);
                }
#pragma unroll
                for (int t = 0; t < 8; ++t) {
                    const int j = 2 * t + half;
                    const bool valid = j < rem;
                    float a = bf2f((ushort)(g[t] & 0xffffu));
                    float b = bf2f((ushort)(g[t] >> 16));
                    const float am = valid ? a : 0.f;
                    const float bm = valid ? b : 0.f;
                    s0 += am; q0 = fmaf(am, am, q0);
                    s1 += bm; q1 = fmaf(bm, bm, q1);
                    m0 = fmaxf(m0, valid ? a : -INFINITY);
                    m1v = fmaxf(m1v, valid ? b : -INFINITY);
                }
            }
        }
        s0 += __shfl_xor(s0, 32, 64);  s1 += __shfl_xor(s1, 32, 64);
        q0 += __shfl_xor(q0, 32, 64);  q1 += __shfl_xor(q1, 32, 64);
        m0  = fmaxf(m0,  __shfl_xor(m0, 32, 64));
        m1v = fmaxf(m1v, __shfl_xor(m1v, 32, 64));

        const float cf = (cnt > 0) ? (float)cnt : 1.f;
        const float inv = 1.f / cf;
        const float mean0 = s0 * inv, mean1 = s1 * inv;
        float v0 = q0 * inv - mean0 * mean0; if (v0 < 0.f) v0 = 0.f;
        float v1 = q1 * inv - mean1 * mean1; if (v1 < 0.f) v1 = 0.f;
        const float sd0 = sqrtf(v0 + EPS), sd1 = sqrtf(v1 + EPS);
        if (cnt == 0) { m0 = 0.f; m1v = 0.f; }

        char* rowp = (char*)&stw[nn][0];
        const int sw = (nn & 7) << 4;
        if (half == 0) {
            *(uint*)(rowp + ((0 + (int)lanoff) ^ sw))   = packbf(s0, s1);
            *(uint*)(rowp + ((256 + (int)lanoff) ^ sw)) = packbf(m0, m1v);
        } else {
            *(uint*)(rowp + ((128 + (int)lanoff) ^ sw)) = packbf(mean0, mean1);
            *(uint*)(rowp + ((384 + (int)lanoff) ^ sw)) = packbf(sd0, sd1);
        }
    }

    // MFMA combine for this pass (accumulates into acc)
    const int r = lane & 15, c = lane >> 4;
    const char* arow = (const char*)&stw[r][0];
    const int asw = (r & 7) << 4;
#pragma unroll
    for (int kt = 0; kt < 8; ++kt) {
        bf16x8 a = *(const bf16x8*)(arow + ((kt * 64 + c * 16) ^ asw));
#pragma unroll
        for (int nt = 0; nt < 4; ++nt) {
            bf16x8 b = *(const bf16x8*)&wt[(nt * 16 + r) * 256 + kt * 32 + c * 8];
            acc[nt] = __builtin_amdgcn_mfma_f32_16x16x32_bf16(a, b, acc[nt], 0, 0, 0);
        }
    }
}

// ---------------------------------------------------------------------------
// K3: fused dual-PNA + relu + LayerNorm. One wave = 16 nodes.
// acc = A1@W1 + A2@W2 (bias added in epilogue), then relu + LN, write out.
// LDS: 8 waves x 16 x 256 bf16 = 64 KB (per-wave private, reused across passes).
// ---------------------------------------------------------------------------
__global__ __launch_bounds__(512, 4) void pna_fused(
    const ushort* __restrict__ msg1, const int* __restrict__ rptr1,
    const int* __restrict__ col1, const ushort* __restrict__ wt1,
    const float* __restrict__ b1,
    const ushort* __restrict__ msg2, const int* __restrict__ rptr2,
    const int* __restrict__ col2, const ushort* __restrict__ wt2,
    const float* __restrict__ b2,
    const float* __restrict__ gamma, const float* __restrict__ beta,
    float* __restrict__ out, int n, int E1, int E2)
{
    __shared__ ushort st[8][16][256];  // 64 KB
    const int tid = threadIdx.x;
    const int wv = tid >> 6, lane = tid & 63;
    const int nodebase = blockIdx.x * 128 + wv * 16;

    int rpidx = nodebase + (lane & 31);
    if (rpidx > n) rpidx = n;
    const int rpv1 = rptr1[rpidx];
    const int rpv2 = rptr2[rpidx];

    f32x4 acc[4] = {{0.f,0.f,0.f,0.f},{0.f,0.f,0.f,0.f},
                    {0.f,0.f,0.f,0.f},{0.f,0.f,0.f,0.f}};

    agg_pass(msg1, col1, wt1, rpv1, st[wv], acc, nodebase, lane, n, E1);
    agg_pass(msg2, col2, wt2, rpv2, st[wv], acc, nodebase, lane, n, E2);

    // ---- epilogue: bias, relu, LayerNorm, store ----
    const int r = lane & 15, c = lane >> 4;
    float biasv[4], gmv[4], btv[4];
#pragma unroll
    for (int nt = 0; nt < 4; ++nt) {
        biasv[nt] = b1[nt * 16 + r] + b2[nt * 16 + r];
        gmv[nt] = gamma[nt * 16 + r];
        btv[nt] = beta[nt * 16 + r];
    }
#pragma unroll
    for (int e = 0; e < 4; ++e) {
        const int i = nodebase + c * 4 + e;
        float v[4];
        float sum = 0.f;
#pragma unroll
        for (int nt = 0; nt < 4; ++nt) {
            float t = fmaxf(acc[nt][e] + biasv[nt], 0.f);
            v[nt] = t;
            sum += t;
        }
        sum += __shfl_xor(sum, 1);
        sum += __shfl_xor(sum, 2);
        sum += __shfl_xor(sum, 4);
        sum += __shfl_xor(sum, 8);
        const float mu = sum * (1.f / 64.f);
        float sqs = 0.f;
#pragma unroll
        for (int nt = 0; nt < 4; ++nt) {
            float d = v[nt] - mu;
            sqs += d * d;
        }
        sqs += __shfl_xor(sqs, 1);
        sqs += __shfl_xor(sqs, 2);
        sqs += __shfl_xor(sqs, 4);
        sqs += __shfl_xor(sqs, 8);
        const float rs = rsqrtf(sqs * (1.f / 64.f) + EPS);
        if (i < n) {
#pragma unroll
            for (int nt = 0; nt < 4; ++nt)
                out[(size_t)i * 64 + nt * 16 + r] =
                    (v[nt] - mu) * rs * gmv[nt] + btv[nt];
        }
    }
}

// ---------------------------------------------------------------------------
extern "C" void kernel_launch(void* const* d_in, const int* in_sizes, int n_in,
                              void* d_out, int out_size, void* d_ws, size_t ws_size,
                              hipStream_t stream)
{
    const float* x     = (const float*)d_in[0];
    const float* w1    = (const float*)d_in[1];
    const float* w2    = (const float*)d_in[2];
    const float* pw1   = (const float*)d_in[3];
    const float* pb1   = (const float*)d_in[4];
    const float* pw2   = (const float*)d_in[5];
    const float* pb2   = (const float*)d_in[6];
    const float* gamma = (const float*)d_in[7];
    const float* beta  = (const float*)d_in[8];
    const int* nb_row  = (const int*)d_in[9];
    const int* nb_col  = (const int*)d_in[10];
    const int* cci_row = (const int*)d_in[11];
    const int* cci_col = (const int*)d_in[12];

    const int n  = in_sizes[0] / 64;   // 100000
    const int E1 = in_sizes[9];        // 1,000,000
    const int E2 = in_sizes[11];

    // workspace: msg1/msg2 bf16 [n*64] | ptr1/ptr2 [n+1] | wt1/wt2 [16384] |
    //            wtl1/wtl2 [4096]
    char* p = (char*)d_ws;
    ushort* msg1 = (ushort*)p;  p += (size_t)n * 64 * sizeof(ushort);
    ushort* msg2 = (ushort*)p;  p += (size_t)n * 64 * sizeof(ushort);
    int* ptr1 = (int*)p;        p += (size_t)(n + 1) * sizeof(int);
    int* ptr2 = (int*)p;        p += (size_t)(n + 1) * sizeof(int);
    p = (char*)(((uintptr_t)p + 63) & ~(uintptr_t)63);
    ushort* wt1 = (ushort*)p;   p += 16384 * sizeof(ushort);
    ushort* wt2 = (ushort*)p;   p += 16384 * sizeof(ushort);
    ushort* wtl1 = (ushort*)p;  p += 4096 * sizeof(ushort);
    ushort* wtl2 = (ushort*)p;
    float* outf = (float*)d_out;

    build_rowptr<<<(E1 + 255) / 256, 256, 0, stream>>>(nb_row, ptr1, E1, n);
    build_rowptr<<<(E2 + 255) / 256, 256, 0, stream>>>(cci_row, ptr2, E2, n);
    prep_w<<<64, 256, 0, stream>>>(pw1, pw2, w1, w2, wt1, wt2, wtl1, wtl2);
    linear_mfma<<<(n + 127) / 128, 512, 0, stream>>>(x, wtl1, wtl2, msg1, msg2, n);

    pna_fused<<<(n + 127) / 128, 512, 0, stream>>>(
        msg1, ptr1, nb_col, wt1, pb1,
        msg2, ptr2, cci_col, wt2, pb2,
        gamma, beta, outf, n, E1, E2);
}